// Round 16
// baseline (114.060 us; speedup 1.0000x reference)
//
#include <hip/hip_runtime.h>
#include <hip/hip_bf16.h>

namespace {
constexpr int N = 16384;
constexpr int K = 2048;
constexpr int D = 1000;
constexpr int RB = 512;            // fp4 row bytes (1024 elems * 0.5 B)
constexpr size_t ND = (size_t)N * D;
constexpr float WSCALE4 = 8192.0f; // codebook pre-scale: |w|max*8192 = 4.0 (fp4 grid top 6)

// workspace layout
constexpr size_t OFF_BEST   = 0;                               // N * u64
constexpr size_t OFF_COUNTS = OFF_BEST + (size_t)N * 8;        // K * u32
constexpr size_t HDR_BYTES  = OFF_COUNTS + (size_t)K * 4;      // zeroed by init_kernel
constexpr size_t OFF_QPART  = HDR_BYTES;                       // 8192 qs partials
constexpr size_t OFF_XNORM  = OFF_QPART + 8448 * 4;            // N f32 |x|^2
constexpr size_t OFF_XQ     = OFF_XNORM + (size_t)N * 4;       // N*RB fp4
constexpr size_t OFF_WQ     = OFF_XQ + (size_t)N * RB;         // K*RB fp4
constexpr size_t OFF_WNORM  = OFF_WQ + (size_t)K * RB;         // K f32
}

typedef __attribute__((ext_vector_type(8))) int int8v;
typedef __attribute__((ext_vector_type(4))) int int4v;
typedef __attribute__((ext_vector_type(16))) float f32x16;

typedef const __attribute__((address_space(1))) unsigned int* gp_t;
typedef __attribute__((address_space(3))) unsigned int* lp_t;

// zero best[] + counts[] (139264 B = 34 blocks * 256 threads * 16 B)
__global__ __launch_bounds__(256) void init_kernel(uint4* __restrict__ p) {
  p[blockIdx.x * 256 + threadIdx.x] = make_uint4(0u, 0u, 0u, 0u);
}

// fp4 e2m1 encode: grid {0,.5,1,1.5,2,3,4,6}, RTE thresholds
__device__ inline unsigned int fp4nib(float v) {
  float u = fabsf(v);
  unsigned int s = (__float_as_uint(v) >> 28) & 8u;   // sign -> bit 3
  unsigned int c = (u >= 0.25f) + (u >= 0.75f) + (u >= 1.25f) + (u >= 1.75f)
                 + (u >= 2.5f) + (u >= 3.5f) + (u >= 5.0f);
  return s | c;
}

// FUSED: read X once -> outq (x+(q-x), q=W[label]) via LDS-staged DENSE stores,
// Xq fp4, qs partials, xnorm. Block = 2 rows.
__global__ __launch_bounds__(256) void fuse_kernel(const float* __restrict__ X,
                                                   const float* __restrict__ W,
                                                   const int* __restrict__ label,
                                                   unsigned int* __restrict__ Xq,
                                                   float* __restrict__ outq,
                                                   float* __restrict__ qpart,
                                                   float* __restrict__ xnorm) {
  __shared__ __attribute__((aligned(16))) float ost[2000];   // block's 2 out rows
  __shared__ float sq[4], sx[4];
  const int tid = threadIdx.x;
  const int h = tid >> 7;
  const int j = tid & 127;
  const int r = blockIdx.x * 2 + h;
  const int lab = label[r];
  float qs = 0.f, xn = 0.f;
  unsigned int pack = 0;
  if (j < 125) {
    const float* xr = X + (size_t)r * D + (j << 3);
    const float* qr = W + (size_t)lab * D + (j << 3);
    float4 x0 = *reinterpret_cast<const float4*>(xr);
    float4 x1 = *reinterpret_cast<const float4*>(xr + 4);
    float4 q0 = *reinterpret_cast<const float4*>(qr);
    float4 q1 = *reinterpret_cast<const float4*>(qr + 4);
    float* o = ost + h * 1000 + (j << 3);
    o[0] = x0.x + (q0.x - x0.x);  o[1] = x0.y + (q0.y - x0.y);
    o[2] = x0.z + (q0.z - x0.z);  o[3] = x0.w + (q0.w - x0.w);
    o[4] = x1.x + (q1.x - x1.x);  o[5] = x1.y + (q1.y - x1.y);
    o[6] = x1.z + (q1.z - x1.z);  o[7] = x1.w + (q1.w - x1.w);
    float d;
    d = q0.x - x0.x; qs += d * d;  d = q0.y - x0.y; qs += d * d;
    d = q0.z - x0.z; qs += d * d;  d = q0.w - x0.w; qs += d * d;
    d = q1.x - x1.x; qs += d * d;  d = q1.y - x1.y; qs += d * d;
    d = q1.z - x1.z; qs += d * d;  d = q1.w - x1.w; qs += d * d;
    xn += x0.x*x0.x + x0.y*x0.y + x0.z*x0.z + x0.w*x0.w
        + x1.x*x1.x + x1.y*x1.y + x1.z*x1.z + x1.w*x1.w;
    pack  = fp4nib(x0.x);        pack |= fp4nib(x0.y) << 4;
    pack |= fp4nib(x0.z) << 8;   pack |= fp4nib(x0.w) << 12;
    pack |= fp4nib(x1.x) << 16;  pack |= fp4nib(x1.y) << 20;
    pack |= fp4nib(x1.z) << 24;  pack |= fp4nib(x1.w) << 28;
  }
  Xq[(size_t)r * 128 + j] = pack;   // dense per instruction; zero pad cols 125..127
  #pragma unroll
  for (int off = 32; off; off >>= 1) {
    qs += __shfl_down(qs, off);
    xn += __shfl_down(xn, off);
  }
  const int wv = tid >> 6;
  if ((tid & 63) == 0) { sq[wv] = qs; sx[wv] = xn; }
  __syncthreads();
  if (tid == 0) {
    qpart[blockIdx.x] = sq[0] + sq[1] + sq[2] + sq[3];
    xnorm[blockIdx.x * 2] = sx[0] + sx[1];
  }
  if (tid == 128) xnorm[blockIdx.x * 2 + 1] = sx[2] + sx[3];
  // DENSE outq store: 2 rows contiguous (2000 floats); lane stride 4 B.
  const size_t ob = (size_t)blockIdx.x * 2000;
  #pragma unroll
  for (int kk = 0; kk < 8; ++kk) {
    const int idx = kk * 256 + tid;
    if (idx < 2000) outq[ob + idx] = ost[idx];
  }
}

// fused: W fp32 -> fp4 (scaled) AND |w_k|^2 (from exact fp32). One wave per row.
__global__ __launch_bounds__(256) void conv_wnorm_kernel(const float* __restrict__ W,
                                                         unsigned int* __restrict__ dst,
                                                         float* __restrict__ wnorm) {
  const int tid = threadIdx.x;
  const int wv = tid >> 6;
  const int lane = tid & 63;
  const int r = blockIdx.x * 4 + wv;
  const float* p = W + (size_t)r * D;
  float s = 0.f;
  #pragma unroll
  for (int h = 0; h < 2; ++h) {
    const int c = lane + h * 64;
    unsigned int out = 0;
    if (c < 125) {
      const float* q = p + (c << 3);
      float4 v0 = *reinterpret_cast<const float4*>(q);
      float4 v1 = *reinterpret_cast<const float4*>(q + 4);
      s += v0.x*v0.x + v0.y*v0.y + v0.z*v0.z + v0.w*v0.w
         + v1.x*v1.x + v1.y*v1.y + v1.z*v1.z + v1.w*v1.w;
      out  = fp4nib(v0.x * WSCALE4);
      out |= fp4nib(v0.y * WSCALE4) << 4;
      out |= fp4nib(v0.z * WSCALE4) << 8;
      out |= fp4nib(v0.w * WSCALE4) << 12;
      out |= fp4nib(v1.x * WSCALE4) << 16;
      out |= fp4nib(v1.y * WSCALE4) << 20;
      out |= fp4nib(v1.z * WSCALE4) << 24;
      out |= fp4nib(v1.w * WSCALE4) << 28;
    }
    dst[(size_t)r * 128 + c] = out;
  }
  #pragma unroll
  for (int off = 32; off; off >>= 1) s += __shfl_down(s, off);
  if (lane == 0) wnorm[r] = s;
}

// Reoriented argmin: D = Wq4 . Xq4^T via MX-fp4 32x32x64 MFMA (FMT=4: e2m1).
// 3-buffer LDS, 2-deep prefetch, counted vmcnt(6) — PLUS fused encodings:
// per macro-step, 8 dense nontemporal u64 stores (1/16th of the block's 64
// one-hot rows) issued AFTER the barrier, BEFORE STAGE(T+2). In-order VMEM
// retirement => next step's vmcnt(6) drains these stores (a full KBODY of
// slack) and still leaves STAGE(T+2) in flight. Uses argmin's idle HBM pipe.
__global__ __launch_bounds__(512, 1) void argmin_kernel(const unsigned char* __restrict__ Xq,
                                                        const unsigned char* __restrict__ Wq,
                                                        const float* __restrict__ wnorm,
                                                        const int* __restrict__ label,
                                                        unsigned long long* __restrict__ enc,
                                                        unsigned int* __restrict__ counts,
                                                        unsigned long long* __restrict__ best) {
  constexpr int BUFB = 49152;
  __shared__ __attribute__((aligned(16))) unsigned char smem[151552];

  const int tid = threadIdx.x;
  const int bid = blockIdx.x;
  const int w = tid >> 6, l = tid & 63;
  const int wr = w >> 1;
  const int wx = w & 1;
  const int lc = l & 31;
  const int lh = l >> 5;
  const int w0 = (bid & 1) * 1024;
  const int x0 = (bid >> 1) * 128;

  const int srow = tid >> 3;
  const int schunk = ((tid & 7) ^ (srow & 7)) << 4;
  auto lsm = (__attribute__((address_space(3))) unsigned char*)smem;
  const float* wsm = (const float*)(smem + 147456);

  const int sxo = lc & 7;
  int chv[4];
  #pragma unroll
  for (int tau = 0; tau < 4; ++tau) chv[tau] = (((2 * tau + lh) ^ sxo) << 4);
  int arow[2], brow[2];
  #pragma unroll
  for (int m = 0; m < 2; ++m) {
    arow[m] = (wr * 64 + m * 32 + lc) * 128;
    brow[m] = (wx * 64 + m * 32 + lc) * 128 + 32768;
  }

#define STAGE(Tn, _b) do {                                                               \
    const unsigned char* _gA = Wq + (size_t)(w0 + ((Tn) >> 2) * 256 + srow) * RB         \
                               + ((Tn) & 3) * 128 + schunk;                              \
    const unsigned char* _gB = Xq + (size_t)(x0 + srow) * RB                             \
                               + ((Tn) & 3) * 128 + schunk;                              \
    _Pragma("unroll")                                                                    \
    for (int _i = 0; _i < 4; ++_i)                                                       \
      __builtin_amdgcn_global_load_lds((gp_t)(_gA + (size_t)(64 * _i) * RB),             \
                                       (lp_t)(lsm + (_b) + _i * 8192 + tid * 16), 16, 0, 0);\
    _Pragma("unroll")                                                                    \
    for (int _i = 0; _i < 2; ++_i)                                                       \
      __builtin_amdgcn_global_load_lds((gp_t)(_gB + (size_t)(64 * _i) * RB),             \
                                       (lp_t)(lsm + (_b) + 32768 + _i * 8192 + tid * 16), 16, 0, 0);\
  } while (0)

  // encodings slice for macro-step Tn: 4096 u64 (4 one-hot rows), 8 dense 4-KB stores
#define ENC(Tn) do {                                                                     \
    const size_t _eb = (size_t)bid * 65536 + (size_t)(Tn) * 4096;                        \
    _Pragma("unroll")                                                                    \
    for (int _j = 0; _j < 8; ++_j) {                                                     \
      const size_t _f = _eb + _j * 512 + tid;                                            \
      const int _row = (int)(_f >> 10);                                                  \
      const int _wi = (int)(_f & 1023);                                                  \
      const int _lab = label[_row];                                                      \
      unsigned long long _v = 0ull;                                                      \
      if ((_lab >> 1) == _wi) {                                                          \
        _v = (_lab & 1) ? (0x3F800000ull << 32) : 0x3F800000ull;                         \
        atomicAdd(&counts[_lab], 1u);                                                    \
      }                                                                                  \
      __builtin_nontemporal_store(_v, enc + _f);                                         \
    }                                                                                    \
  } while (0)

#define KBODY(bufb) do {                                                                 \
    _Pragma("unroll")                                                                    \
    for (int tau = 0; tau < 4; ++tau) {                                                  \
      int4v la0 = *reinterpret_cast<const int4v*>(smem + (bufb) + arow[0] + chv[tau]);   \
      int4v la1 = *reinterpret_cast<const int4v*>(smem + (bufb) + arow[1] + chv[tau]);   \
      int4v lb0 = *reinterpret_cast<const int4v*>(smem + (bufb) + brow[0] + chv[tau]);   \
      int4v lb1 = *reinterpret_cast<const int4v*>(smem + (bufb) + brow[1] + chv[tau]);   \
      int8v a0, a1, b0, b1;                                                              \
      a0[0]=la0[0];a0[1]=la0[1];a0[2]=la0[2];a0[3]=la0[3];                               \
      a0[4]=la0[0];a0[5]=la0[1];a0[6]=la0[2];a0[7]=la0[3];                               \
      a1[0]=la1[0];a1[1]=la1[1];a1[2]=la1[2];a1[3]=la1[3];                               \
      a1[4]=la1[0];a1[5]=la1[1];a1[6]=la1[2];a1[7]=la1[3];                               \
      b0[0]=lb0[0];b0[1]=lb0[1];b0[2]=lb0[2];b0[3]=lb0[3];                               \
      b0[4]=lb0[0];b0[5]=lb0[1];b0[6]=lb0[2];b0[7]=lb0[3];                               \
      b1[0]=lb1[0];b1[1]=lb1[1];b1[2]=lb1[2];b1[3]=lb1[3];                               \
      b1[4]=lb1[0];b1[5]=lb1[1];b1[6]=lb1[2];b1[7]=lb1[3];                               \
      __builtin_amdgcn_s_setprio(1);                                                     \
      acc[0][0] = __builtin_amdgcn_mfma_scale_f32_32x32x64_f8f6f4(a0, b0, acc[0][0], 4, 4, 0, 0x7f7f7f7f, 0, 0x7f7f7f7f); \
      acc[0][1] = __builtin_amdgcn_mfma_scale_f32_32x32x64_f8f6f4(a0, b1, acc[0][1], 4, 4, 0, 0x7f7f7f7f, 0, 0x7f7f7f7f); \
      acc[1][0] = __builtin_amdgcn_mfma_scale_f32_32x32x64_f8f6f4(a1, b0, acc[1][0], 4, 4, 0, 0x7f7f7f7f, 0, 0x7f7f7f7f); \
      acc[1][1] = __builtin_amdgcn_mfma_scale_f32_32x32x64_f8f6f4(a1, b1, acc[1][1], 4, 4, 0, 0x7f7f7f7f, 0, 0x7f7f7f7f); \
      __builtin_amdgcn_s_setprio(0);                                                     \
    }                                                                                    \
  } while (0)

#define FOLD(ct_) do {                                                                   \
    _Pragma("unroll")                                                                    \
    for (int m = 0; m < 2; ++m) {                                                        \
      _Pragma("unroll")                                                                  \
      for (int r = 0; r < 16; ++r) {                                                     \
        const int wl = wr * 64 + m * 32 + (r & 3) + 8 * (r >> 2) + 4 * lh;               \
        const float wn = wsm[(ct_) * 256 + wl];                                          \
        const unsigned int nw = ~(unsigned int)(w0 + (ct_) * 256 + wl);                  \
        float s0 = dsc * acc[m][0][r] - wn;                                              \
        float s1 = dsc * acc[m][1][r] - wn;                                              \
        unsigned int u0 = __float_as_uint(s0);                                           \
        u0 = (u0 & 0x80000000u) ? ~u0 : (u0 | 0x80000000u);                              \
        unsigned int u1 = __float_as_uint(s1);                                           \
        u1 = (u1 & 0x80000000u) ? ~u1 : (u1 | 0x80000000u);                              \
        unsigned long long p0 = ((unsigned long long)u0 << 32) | nw;                     \
        unsigned long long p1 = ((unsigned long long)u1 << 32) | nw;                     \
        if (p0 > best0) best0 = p0;                                                      \
        if (p1 > best1) best1 = p1;                                                      \
        acc[m][0][r] = 0.f;                                                              \
        acc[m][1][r] = 0.f;                                                              \
      }                                                                                  \
    }                                                                                    \
  } while (0)

  f32x16 acc[2][2];
  #pragma unroll
  for (int m = 0; m < 2; ++m)
    #pragma unroll
    for (int n = 0; n < 2; ++n)
      #pragma unroll
      for (int r = 0; r < 16; ++r) acc[m][n][r] = 0.f;

  const float dsc = 2.0f / WSCALE4;
  unsigned long long best0 = 0ull, best1 = 0ull;

  __builtin_amdgcn_global_load_lds((gp_t)(wnorm + w0 + tid),
                                   (lp_t)(lsm + 147456 + tid * 4), 4, 0, 0);
  __builtin_amdgcn_global_load_lds((gp_t)(wnorm + w0 + 512 + tid),
                                   (lp_t)(lsm + 147456 + 2048 + tid * 4), 4, 0, 0);
  STAGE(0, 0);
  STAGE(1, BUFB);

  int bufb = 0;
  int sb = 2 * BUFB;
  for (int T = 0; T < 15; ++T) {
    asm volatile("s_waitcnt vmcnt(6)" ::: "memory");
    __builtin_amdgcn_s_barrier();
    __builtin_amdgcn_sched_barrier(0);
    ENC(T);                          // stores issued BEFORE next stage loads
    if (T + 2 < 16) STAGE(T + 2, sb);
    KBODY(bufb);
    if ((T & 3) == 3) FOLD(T >> 2);
    bufb = (bufb == 2 * BUFB) ? 0 : bufb + BUFB;
    sb = (sb == 2 * BUFB) ? 0 : sb + BUFB;
  }
  {
    asm volatile("s_waitcnt vmcnt(0)" ::: "memory");
    __builtin_amdgcn_s_barrier();
    __builtin_amdgcn_sched_barrier(0);
    ENC(15);
    KBODY(bufb);
    FOLD(3);
  }
#undef STAGE
#undef ENC
#undef KBODY
#undef FOLD

  unsigned long long o0 = __shfl_xor(best0, 32);
  if (o0 > best0) best0 = o0;
  unsigned long long o1 = __shfl_xor(best1, 32);
  if (o1 > best1) best1 = o1;
  if (lh == 0) {
    atomicMax(best + x0 + wx * 64 + lc, best0);
    atomicMax(best + x0 + wx * 64 + 32 + lc, best1);
  }
}

// merged xs + final: xs from score-recovery (orderable transform inverted),
// entropy from counts, qs from partials. One block, 1024 threads.
__global__ __launch_bounds__(1024) void final_kernel(const unsigned long long* __restrict__ best,
                                                     const int* __restrict__ label,
                                                     const float* __restrict__ xnorm,
                                                     const unsigned int* __restrict__ counts,
                                                     const float* __restrict__ qpart,
                                                     float* __restrict__ out) {
  const int tid = threadIdx.x;
  float xs = 0.f, e = 0.f, qs = 0.f;
  for (int r = tid; r < N; r += 1024) {
    const unsigned long long b = best[r];
    const int k = (int)(~(unsigned int)(b & 0xffffffffull));
    if (label[r] != k) {
      unsigned int u = (unsigned int)(b >> 32);
      unsigned int s = (u >> 31) ? (u ^ 0x80000000u) : ~u;
      xs += xnorm[r] - __uint_as_float(s);
    }
  }
  for (int k = tid; k < K; k += 1024) {
    float p = (float)counts[k] * (1.0f / (float)N);
    e += p * logf(p + 1e-10f);
  }
  for (int i = tid; i < 8192; i += 1024) qs += qpart[i];
  #pragma unroll
  for (int off = 32; off; off >>= 1) {
    xs += __shfl_down(xs, off);
    e += __shfl_down(e, off);
    qs += __shfl_down(qs, off);
  }
  __shared__ float sx[16], se[16], sq[16];
  if ((tid & 63) == 0) { sx[tid >> 6] = xs; se[tid >> 6] = e; sq[tid >> 6] = qs; }
  __syncthreads();
  if (tid == 0) {
    float tx = 0.f, te = 0.f, tq = 0.f;
    #pragma unroll
    for (int i = 0; i < 16; ++i) { tx += sx[i]; te += se[i]; tq += sq[i]; }
    const float inv = 1.0f / (float)((long long)N * D);
    out[0] = 1.25f * tq * inv - 1.1f * tx * inv;   // loss
    out[1 + ND] = expf(-te);                       // perplexity
  }
}

extern "C" void kernel_launch(void* const* d_in, const int* in_sizes, int n_in,
                              void* d_out, int out_size, void* d_ws, size_t ws_size,
                              hipStream_t stream) {
  const float* X = (const float*)d_in[0];
  const int* label = (const int*)d_in[1];
  const float* W = (const float*)d_in[2];
  float* out = (float*)d_out;
  char* ws = (char*)d_ws;

  unsigned long long* best = (unsigned long long*)(ws + OFF_BEST);
  unsigned int* counts = (unsigned int*)(ws + OFF_COUNTS);
  float* qpart = (float*)(ws + OFF_QPART);
  float* xnorm = (float*)(ws + OFF_XNORM);
  unsigned char* Xq = (unsigned char*)(ws + OFF_XQ);
  unsigned char* Wq = (unsigned char*)(ws + OFF_WQ);
  float* wnorm = (float*)(ws + OFF_WNORM);

  init_kernel<<<34, 256, 0, stream>>>((uint4*)ws);   // zero best+counts (139264 B)

  fuse_kernel<<<N / 2, 256, 0, stream>>>(X, W, label, (unsigned int*)Xq,
                                         out + 1, qpart, xnorm);
  conv_wnorm_kernel<<<K / 4, 256, 0, stream>>>(W, (unsigned int*)Wq, wnorm);
  argmin_kernel<<<256, 512, 0, stream>>>(Xq, Wq, wnorm, label,
                                         (unsigned long long*)(out + 2 + ND),
                                         counts, best);
  final_kernel<<<1, 1024, 0, stream>>>(best, label, xnorm, counts, qpart, out);
}

// Round 17
// 98.512 us; speedup vs baseline: 1.1578x; 1.1578x over previous
//
#include <hip/hip_runtime.h>
#include <hip/hip_bf16.h>

namespace {
constexpr int N = 16384;
constexpr int K = 2048;
constexpr int D = 1000;
constexpr int RB = 512;            // fp4 row bytes (1024 elems * 0.5 B)
constexpr size_t ND = (size_t)N * D;
constexpr float WSCALE4 = 8192.0f; // codebook pre-scale: |w|max*8192 = 4.0 (fp4 grid top 6)

// workspace layout
constexpr size_t OFF_BEST   = 0;                               // N * u64 (zeroed in prepass)
constexpr size_t OFF_QPART  = OFF_BEST + (size_t)N * 8;        // 8192 qs partials
constexpr size_t OFF_XNORM  = OFF_QPART + 8448 * 4;            // N f32 |x|^2
constexpr size_t OFF_XQ     = OFF_XNORM + (size_t)N * 4;       // N*RB fp4
constexpr size_t OFF_WQ     = OFF_XQ + (size_t)N * RB;         // K*RB fp4
constexpr size_t OFF_WNORM  = OFF_WQ + (size_t)K * RB;         // K f32
}

typedef __attribute__((ext_vector_type(8))) int int8v;
typedef __attribute__((ext_vector_type(4))) int int4v;
typedef __attribute__((ext_vector_type(16))) float f32x16;

typedef const __attribute__((address_space(1))) unsigned int* gp_t;
typedef __attribute__((address_space(3))) unsigned int* lp_t;

// fp4 e2m1 encode: grid {0,.5,1,1.5,2,3,4,6}, RTE thresholds
__device__ inline unsigned int fp4nib(float v) {
  float u = fabsf(v);
  unsigned int s = (__float_as_uint(v) >> 28) & 8u;   // sign -> bit 3
  unsigned int c = (u >= 0.25f) + (u >= 0.75f) + (u >= 1.25f) + (u >= 1.75f)
                 + (u >= 2.5f) + (u >= 3.5f) + (u >= 5.0f);
  return s | c;
}

// PREPASS: one launch, block-range branch over 4 independent jobs.
//  bid in [0,16384): pair p=bid>>1. even -> FUSE rows {2p,2p+1} (read-heavy);
//                    odd -> ENC one-hot rows {2p,2p+1} (write-heavy).
//                    Interleaved so read/write pipes overlap across the grid.
//  bid in [16384,16896): conv_wnorm row quad (bid-16384).
//  bid in [16896,16928): zero best[] (32 blocks x 256 x 16 B = 131072 B).
// No intra-kernel producer/consumer pairs (histogram moved to final_kernel).
__global__ __launch_bounds__(256) void prepass_kernel(const float* __restrict__ X,
                                                      const float* __restrict__ W,
                                                      const int* __restrict__ label,
                                                      unsigned int* __restrict__ Xq,
                                                      unsigned int* __restrict__ Wq,
                                                      float* __restrict__ wnorm,
                                                      float* __restrict__ outq,
                                                      float* __restrict__ qpart,
                                                      float* __restrict__ xnorm,
                                                      unsigned long long* __restrict__ enc,
                                                      uint4* __restrict__ bestz) {
  __shared__ __attribute__((aligned(16))) float ost[2000];
  __shared__ float sq[4], sx[4];
  const int bid = blockIdx.x;
  const int tid = threadIdx.x;

  if (bid < 16384) {
    const int p = bid >> 1;
    if ((bid & 1) == 0) {
      // ---- FUSE: read X once -> outq (x+(q-x), q=W[label]) dense via LDS,
      //      Xq fp4, qs partial, xnorm. Rows 2p, 2p+1.
      const int h = tid >> 7;
      const int j = tid & 127;
      const int r = p * 2 + h;
      const int lab = label[r];
      float qs = 0.f, xn = 0.f;
      unsigned int pack = 0;
      if (j < 125) {
        const float* xr = X + (size_t)r * D + (j << 3);
        const float* qr = W + (size_t)lab * D + (j << 3);
        float4 x0 = *reinterpret_cast<const float4*>(xr);
        float4 x1 = *reinterpret_cast<const float4*>(xr + 4);
        float4 q0 = *reinterpret_cast<const float4*>(qr);
        float4 q1 = *reinterpret_cast<const float4*>(qr + 4);
        float* o = ost + h * 1000 + (j << 3);
        o[0] = x0.x + (q0.x - x0.x);  o[1] = x0.y + (q0.y - x0.y);
        o[2] = x0.z + (q0.z - x0.z);  o[3] = x0.w + (q0.w - x0.w);
        o[4] = x1.x + (q1.x - x1.x);  o[5] = x1.y + (q1.y - x1.y);
        o[6] = x1.z + (q1.z - x1.z);  o[7] = x1.w + (q1.w - x1.w);
        float d;
        d = q0.x - x0.x; qs += d * d;  d = q0.y - x0.y; qs += d * d;
        d = q0.z - x0.z; qs += d * d;  d = q0.w - x0.w; qs += d * d;
        d = q1.x - x1.x; qs += d * d;  d = q1.y - x1.y; qs += d * d;
        d = q1.z - x1.z; qs += d * d;  d = q1.w - x1.w; qs += d * d;
        xn += x0.x*x0.x + x0.y*x0.y + x0.z*x0.z + x0.w*x0.w
            + x1.x*x1.x + x1.y*x1.y + x1.z*x1.z + x1.w*x1.w;
        pack  = fp4nib(x0.x);        pack |= fp4nib(x0.y) << 4;
        pack |= fp4nib(x0.z) << 8;   pack |= fp4nib(x0.w) << 12;
        pack |= fp4nib(x1.x) << 16;  pack |= fp4nib(x1.y) << 20;
        pack |= fp4nib(x1.z) << 24;  pack |= fp4nib(x1.w) << 28;
      }
      Xq[(size_t)r * 128 + j] = pack;
      #pragma unroll
      for (int off = 32; off; off >>= 1) {
        qs += __shfl_down(qs, off);
        xn += __shfl_down(xn, off);
      }
      const int wv = tid >> 6;
      if ((tid & 63) == 0) { sq[wv] = qs; sx[wv] = xn; }
      __syncthreads();
      if (tid == 0) {
        qpart[p] = sq[0] + sq[1] + sq[2] + sq[3];
        xnorm[p * 2] = sx[0] + sx[1];
      }
      if (tid == 128) xnorm[p * 2 + 1] = sx[2] + sx[3];
      const size_t ob = (size_t)p * 2000;
      #pragma unroll
      for (int kk = 0; kk < 8; ++kk) {
        const int idx = kk * 256 + tid;
        if (idx < 2000) outq[ob + idx] = ost[idx];
      }
    } else {
      // ---- ENC: one-hot rows 2p, 2p+1 (2048 u64, dense nontemporal stores)
      const size_t eb = (size_t)p * 2048;
      #pragma unroll
      for (int j = 0; j < 8; ++j) {
        const size_t f = eb + (size_t)j * 256 + tid;
        const int row = (int)(f >> 10);
        const int wi = (int)(f & 1023);
        const int lab = label[row];
        unsigned long long v = 0ull;
        if ((lab >> 1) == wi) v = (lab & 1) ? (0x3F800000ull << 32) : 0x3F800000ull;
        __builtin_nontemporal_store(v, enc + f);
      }
    }
  } else if (bid < 16896) {
    // ---- conv_wnorm: W fp32 -> fp4 (scaled) + |w|^2. One wave per row.
    const int wv = tid >> 6;
    const int lane = tid & 63;
    const int r = (bid - 16384) * 4 + wv;
    const float* pw = W + (size_t)r * D;
    float s = 0.f;
    #pragma unroll
    for (int h = 0; h < 2; ++h) {
      const int c = lane + h * 64;
      unsigned int out = 0;
      if (c < 125) {
        const float* q = pw + (c << 3);
        float4 v0 = *reinterpret_cast<const float4*>(q);
        float4 v1 = *reinterpret_cast<const float4*>(q + 4);
        s += v0.x*v0.x + v0.y*v0.y + v0.z*v0.z + v0.w*v0.w
           + v1.x*v1.x + v1.y*v1.y + v1.z*v1.z + v1.w*v1.w;
        out  = fp4nib(v0.x * WSCALE4);
        out |= fp4nib(v0.y * WSCALE4) << 4;
        out |= fp4nib(v0.z * WSCALE4) << 8;
        out |= fp4nib(v0.w * WSCALE4) << 12;
        out |= fp4nib(v1.x * WSCALE4) << 16;
        out |= fp4nib(v1.y * WSCALE4) << 20;
        out |= fp4nib(v1.z * WSCALE4) << 24;
        out |= fp4nib(v1.w * WSCALE4) << 28;
      }
      Wq[(size_t)r * 128 + c] = out;
    }
    #pragma unroll
    for (int off = 32; off; off >>= 1) s += __shfl_down(s, off);
    if (lane == 0) wnorm[r] = s;
  } else {
    // ---- zero best[] (no intra-kernel reader; argmin is a later launch)
    bestz[(bid - 16896) * 256 + tid] = make_uint4(0u, 0u, 0u, 0u);
  }
}

// Reoriented argmin: D = Wq4 . Xq4^T via MX-fp4 32x32x64 MFMA (FMT=4: e2m1).
// 3-buffer LDS, 2-deep prefetch, counted vmcnt(6). Measured: 27.4 us (R11).
// (R15's fused enc-stores REVERTED: stores share the wave's vmcnt counter and
//  put HBM-store retirement on the counted-load critical path -> regression.)
__global__ __launch_bounds__(512, 1) void argmin_kernel(const unsigned char* __restrict__ Xq,
                                                        const unsigned char* __restrict__ Wq,
                                                        const float* __restrict__ wnorm,
                                                        unsigned long long* __restrict__ best) {
  constexpr int BUFB = 49152;
  __shared__ __attribute__((aligned(16))) unsigned char smem[151552];

  const int tid = threadIdx.x;
  const int bid = blockIdx.x;
  const int w = tid >> 6, l = tid & 63;
  const int wr = w >> 1;
  const int wx = w & 1;
  const int lc = l & 31;
  const int lh = l >> 5;
  const int w0 = (bid & 1) * 1024;
  const int x0 = (bid >> 1) * 128;

  const int srow = tid >> 3;
  const int schunk = ((tid & 7) ^ (srow & 7)) << 4;
  auto lsm = (__attribute__((address_space(3))) unsigned char*)smem;
  const float* wsm = (const float*)(smem + 147456);

  const int sxo = lc & 7;
  int chv[4];
  #pragma unroll
  for (int tau = 0; tau < 4; ++tau) chv[tau] = (((2 * tau + lh) ^ sxo) << 4);
  int arow[2], brow[2];
  #pragma unroll
  for (int m = 0; m < 2; ++m) {
    arow[m] = (wr * 64 + m * 32 + lc) * 128;
    brow[m] = (wx * 64 + m * 32 + lc) * 128 + 32768;
  }

#define STAGE(Tn, _b) do {                                                               \
    const unsigned char* _gA = Wq + (size_t)(w0 + ((Tn) >> 2) * 256 + srow) * RB         \
                               + ((Tn) & 3) * 128 + schunk;                              \
    const unsigned char* _gB = Xq + (size_t)(x0 + srow) * RB                             \
                               + ((Tn) & 3) * 128 + schunk;                              \
    _Pragma("unroll")                                                                    \
    for (int _i = 0; _i < 4; ++_i)                                                       \
      __builtin_amdgcn_global_load_lds((gp_t)(_gA + (size_t)(64 * _i) * RB),             \
                                       (lp_t)(lsm + (_b) + _i * 8192 + tid * 16), 16, 0, 0);\
    _Pragma("unroll")                                                                    \
    for (int _i = 0; _i < 2; ++_i)                                                       \
      __builtin_amdgcn_global_load_lds((gp_t)(_gB + (size_t)(64 * _i) * RB),             \
                                       (lp_t)(lsm + (_b) + 32768 + _i * 8192 + tid * 16), 16, 0, 0);\
  } while (0)

#define KBODY(bufb) do {                                                                 \
    _Pragma("unroll")                                                                    \
    for (int tau = 0; tau < 4; ++tau) {                                                  \
      int4v la0 = *reinterpret_cast<const int4v*>(smem + (bufb) + arow[0] + chv[tau]);   \
      int4v la1 = *reinterpret_cast<const int4v*>(smem + (bufb) + arow[1] + chv[tau]);   \
      int4v lb0 = *reinterpret_cast<const int4v*>(smem + (bufb) + brow[0] + chv[tau]);   \
      int4v lb1 = *reinterpret_cast<const int4v*>(smem + (bufb) + brow[1] + chv[tau]);   \
      int8v a0, a1, b0, b1;                                                              \
      a0[0]=la0[0];a0[1]=la0[1];a0[2]=la0[2];a0[3]=la0[3];                               \
      a0[4]=la0[0];a0[5]=la0[1];a0[6]=la0[2];a0[7]=la0[3];                               \
      a1[0]=la1[0];a1[1]=la1[1];a1[2]=la1[2];a1[3]=la1[3];                               \
      a1[4]=la1[0];a1[5]=la1[1];a1[6]=la1[2];a1[7]=la1[3];                               \
      b0[0]=lb0[0];b0[1]=lb0[1];b0[2]=lb0[2];b0[3]=lb0[3];                               \
      b0[4]=lb0[0];b0[5]=lb0[1];b0[6]=lb0[2];b0[7]=lb0[3];                               \
      b1[0]=lb1[0];b1[1]=lb1[1];b1[2]=lb1[2];b1[3]=lb1[3];                               \
      b1[4]=lb1[0];b1[5]=lb1[1];b1[6]=lb1[2];b1[7]=lb1[3];                               \
      __builtin_amdgcn_s_setprio(1);                                                     \
      acc[0][0] = __builtin_amdgcn_mfma_scale_f32_32x32x64_f8f6f4(a0, b0, acc[0][0], 4, 4, 0, 0x7f7f7f7f, 0, 0x7f7f7f7f); \
      acc[0][1] = __builtin_amdgcn_mfma_scale_f32_32x32x64_f8f6f4(a0, b1, acc[0][1], 4, 4, 0, 0x7f7f7f7f, 0, 0x7f7f7f7f); \
      acc[1][0] = __builtin_amdgcn_mfma_scale_f32_32x32x64_f8f6f4(a1, b0, acc[1][0], 4, 4, 0, 0x7f7f7f7f, 0, 0x7f7f7f7f); \
      acc[1][1] = __builtin_amdgcn_mfma_scale_f32_32x32x64_f8f6f4(a1, b1, acc[1][1], 4, 4, 0, 0x7f7f7f7f, 0, 0x7f7f7f7f); \
      __builtin_amdgcn_s_setprio(0);                                                     \
    }                                                                                    \
  } while (0)

#define FOLD(ct_) do {                                                                   \
    _Pragma("unroll")                                                                    \
    for (int m = 0; m < 2; ++m) {                                                        \
      _Pragma("unroll")                                                                  \
      for (int r = 0; r < 16; ++r) {                                                     \
        const int wl = wr * 64 + m * 32 + (r & 3) + 8 * (r >> 2) + 4 * lh;               \
        const float wn = wsm[(ct_) * 256 + wl];                                          \
        const unsigned int nw = ~(unsigned int)(w0 + (ct_) * 256 + wl);                  \
        float s0 = dsc * acc[m][0][r] - wn;                                              \
        float s1 = dsc * acc[m][1][r] - wn;                                              \
        unsigned int u0 = __float_as_uint(s0);                                           \
        u0 = (u0 & 0x80000000u) ? ~u0 : (u0 | 0x80000000u);                              \
        unsigned int u1 = __float_as_uint(s1);                                           \
        u1 = (u1 & 0x80000000u) ? ~u1 : (u1 | 0x80000000u);                              \
        unsigned long long p0 = ((unsigned long long)u0 << 32) | nw;                     \
        unsigned long long p1 = ((unsigned long long)u1 << 32) | nw;                     \
        if (p0 > best0) best0 = p0;                                                      \
        if (p1 > best1) best1 = p1;                                                      \
        acc[m][0][r] = 0.f;                                                              \
        acc[m][1][r] = 0.f;                                                              \
      }                                                                                  \
    }                                                                                    \
  } while (0)

  f32x16 acc[2][2];
  #pragma unroll
  for (int m = 0; m < 2; ++m)
    #pragma unroll
    for (int n = 0; n < 2; ++n)
      #pragma unroll
      for (int r = 0; r < 16; ++r) acc[m][n][r] = 0.f;

  const float dsc = 2.0f / WSCALE4;
  unsigned long long best0 = 0ull, best1 = 0ull;

  __builtin_amdgcn_global_load_lds((gp_t)(wnorm + w0 + tid),
                                   (lp_t)(lsm + 147456 + tid * 4), 4, 0, 0);
  __builtin_amdgcn_global_load_lds((gp_t)(wnorm + w0 + 512 + tid),
                                   (lp_t)(lsm + 147456 + 2048 + tid * 4), 4, 0, 0);
  STAGE(0, 0);
  STAGE(1, BUFB);

  int bufb = 0;
  int sb = 2 * BUFB;
  for (int T = 0; T < 15; ++T) {
    asm volatile("s_waitcnt vmcnt(6)" ::: "memory");
    __builtin_amdgcn_s_barrier();
    __builtin_amdgcn_sched_barrier(0);
    if (T + 2 < 16) STAGE(T + 2, sb);
    KBODY(bufb);
    if ((T & 3) == 3) FOLD(T >> 2);
    bufb = (bufb == 2 * BUFB) ? 0 : bufb + BUFB;
    sb = (sb == 2 * BUFB) ? 0 : sb + BUFB;
  }
  {
    asm volatile("s_waitcnt vmcnt(0)" ::: "memory");
    __builtin_amdgcn_s_barrier();
    __builtin_amdgcn_sched_barrier(0);
    KBODY(bufb);
    FOLD(3);
  }
#undef STAGE
#undef KBODY
#undef FOLD

  unsigned long long o0 = __shfl_xor(best0, 32);
  if (o0 > best0) best0 = o0;
  unsigned long long o1 = __shfl_xor(best1, 32);
  if (o1 > best1) best1 = o1;
  if (lh == 0) {
    atomicMax(best + x0 + wx * 64 + lc, best0);
    atomicMax(best + x0 + wx * 64 + 32 + lc, best1);
  }
}

// final: LDS histogram over label (replaces counts atomics + init), entropy,
// xs via score-recovery, qs from partials. One block, 1024 threads.
__global__ __launch_bounds__(1024) void final_kernel(const unsigned long long* __restrict__ best,
                                                     const int* __restrict__ label,
                                                     const float* __restrict__ xnorm,
                                                     const float* __restrict__ qpart,
                                                     float* __restrict__ out) {
  __shared__ unsigned int cnt[K];
  const int tid = threadIdx.x;
  for (int i = tid; i < K; i += 1024) cnt[i] = 0u;
  __syncthreads();
  float xs = 0.f, qs = 0.f;
  for (int r = tid; r < N; r += 1024) {
    const int lab = label[r];
    atomicAdd(&cnt[lab], 1u);
    const unsigned long long b = best[r];
    const int k = (int)(~(unsigned int)(b & 0xffffffffull));
    if (lab != k) {
      unsigned int u = (unsigned int)(b >> 32);
      unsigned int s = (u >> 31) ? (u ^ 0x80000000u) : ~u;
      xs += xnorm[r] - __uint_as_float(s);
    }
  }
  for (int i = tid; i < 8192; i += 1024) qs += qpart[i];
  __syncthreads();
  float e = 0.f;
  for (int k = tid; k < K; k += 1024) {
    float p = (float)cnt[k] * (1.0f / (float)N);
    e += p * logf(p + 1e-10f);
  }
  #pragma unroll
  for (int off = 32; off; off >>= 1) {
    xs += __shfl_down(xs, off);
    e += __shfl_down(e, off);
    qs += __shfl_down(qs, off);
  }
  __shared__ float sx[16], se[16], sq[16];
  if ((tid & 63) == 0) { sx[tid >> 6] = xs; se[tid >> 6] = e; sq[tid >> 6] = qs; }
  __syncthreads();
  if (tid == 0) {
    float tx = 0.f, te = 0.f, tq = 0.f;
    #pragma unroll
    for (int i = 0; i < 16; ++i) { tx += sx[i]; te += se[i]; tq += sq[i]; }
    const float inv = 1.0f / (float)((long long)N * D);
    out[0] = 1.25f * tq * inv - 1.1f * tx * inv;   // loss
    out[1 + ND] = expf(-te);                       // perplexity
  }
}

extern "C" void kernel_launch(void* const* d_in, const int* in_sizes, int n_in,
                              void* d_out, int out_size, void* d_ws, size_t ws_size,
                              hipStream_t stream) {
  const float* X = (const float*)d_in[0];
  const int* label = (const int*)d_in[1];
  const float* W = (const float*)d_in[2];
  float* out = (float*)d_out;
  char* ws = (char*)d_ws;

  unsigned long long* best = (unsigned long long*)(ws + OFF_BEST);
  float* qpart = (float*)(ws + OFF_QPART);
  float* xnorm = (float*)(ws + OFF_XNORM);
  unsigned char* Xq = (unsigned char*)(ws + OFF_XQ);
  unsigned char* Wq = (unsigned char*)(ws + OFF_WQ);
  float* wnorm = (float*)(ws + OFF_WNORM);

  prepass_kernel<<<16928, 256, 0, stream>>>(X, W, label,
                                            (unsigned int*)Xq, (unsigned int*)Wq,
                                            wnorm, out + 1, qpart, xnorm,
                                            (unsigned long long*)(out + 2 + ND),
                                            (uint4*)best);
  argmin_kernel<<<256, 512, 0, stream>>>(Xq, Wq, wnorm, best);
  final_kernel<<<1, 1024, 0, stream>>>(best, label, xnorm, qpart, out);
}